// Round 3
// baseline (193.621 us; speedup 1.0000x reference)
//
#include <hip/hip_runtime.h>
#include <math.h>

#define BB 1024
#define NN 256
#define VV 200
#define BT 16   // batch rows per k_final block

// d_ws layout (bytes):
//   [0      .. 2400)   g_sum  [3*200] floats
//   [2400   .. 4800)   g_ss   [3*200] floats
//   [4864   .. +2.4MB) g_x    [3][1024][200] floats
#define WS_SUM 0
#define WS_SS  (3 * VV)
#define WS_X_OFF 4864

// ---------------- K1: fused prep + attention + BN-stats-accumulate ----------------
// one block per batch row, 256 threads
__global__ __launch_bounds__(256) void k_attn(
    const float* __restrict__ merged, const float* __restrict__ a,
    const float* __restrict__ upWq, const float* __restrict__ upWk, const float* __restrict__ upWv,
    const float* __restrict__ dnWq, const float* __restrict__ dnWk, const float* __restrict__ dnWv,
    const float* __restrict__ pvWq, const float* __restrict__ pvWk, const float* __restrict__ pvWv,
    float* __restrict__ ws) {
    int b = blockIdx.x;
    int tid = threadIdx.x;
    int lane = tid & 63, wave = tid >> 6;

    __shared__ float sm[NN * 15];          // row features (corrected in place)
    __shared__ float eMq[3 * VV];          // per-head ego@Wq
    __shared__ float eM[35];               // per-head (ego@Wq)@Wk^T : [h0 f0..13 | h1 f0..13 | h2 f0..6]
    __shared__ float part[280];            // 35 dots x 8 partials
    __shared__ float psh[3 * 264];         // softmax p per head (padded stride vs bank conflicts)
    __shared__ float csh[35];              // c[f] per head
    __shared__ float wred[4][3];           // per-wave reduction scratch

    float* g_sum = ws + WS_SUM;
    float* g_ss  = ws + WS_SS;
    float* g_x   = ws + (WS_X_OFF / 4);

    // ---- load row ----
    const float4* mb4 = (const float4*)(merged + (size_t)b * NN * 15);
    float4* sm4 = (float4*)sm;
    for (int i = tid; i < NN * 15 / 4; i += 256) sm4[i] = mb4[i];
    __syncthreads();

    float subj_id = sm[0];
    float subj_loc = sm[2];
    float ab = a[b];
    __syncthreads();   // everyone has read sm[0],sm[2] before corrections

    // ---- in-place corrections: feature 0 and 7 shift, [0,6]=a ----
    {
        int n = tid;
        sm[n * 15 + 0] -= subj_id;
        sm[n * 15 + 7] -= subj_id;
        if (n == 0) sm[6] = ab;
    }
    __syncthreads();

    // ---- phase B: eMq[h][v] = sum_i ego[i]*Wq_h[i][v]  (ego[0]==0, skip i=0) ----
    if (tid < VV) {
        float e1 = sm[1], e2 = sm[2], e3 = sm[3], e4 = sm[4], e5 = sm[5], e6 = sm[6];
        const float* Wqs[3] = {upWq, dnWq, pvWq};
#pragma unroll
        for (int h = 0; h < 3; h++) {
            const float* Wq = Wqs[h];
            float s = e1 * Wq[VV + tid] + e2 * Wq[2 * VV + tid] + e3 * Wq[3 * VV + tid] +
                      e4 * Wq[4 * VV + tid] + e5 * Wq[5 * VV + tid] + e6 * Wq[6 * VV + tid];
            eMq[h * VV + tid] = s;
        }
    }
    __syncthreads();

    // ---- phase C: eM[d] = sum_v eMq[h][v] * Wk_h[f][v], 35 dots x 8 partials ----
    for (int vt = tid; vt < 280; vt += 256) {
        int d = vt >> 3, j = vt & 7;
        int h = d < 14 ? 0 : (d < 28 ? 1 : 2);
        int f = d - (h == 0 ? 0 : (h == 1 ? 14 : 28));
        const float* Wk = h == 0 ? upWk : (h == 1 ? dnWk : pvWk);
        const float* em = eMq + h * VV;
        float s = 0.f;
        for (int v = j; v < VV; v += 8) s += em[v] * Wk[f * VV + v];
        part[d * 8 + j] = s;
    }
    __syncthreads();
    if (tid < 35) {
        float s = 0.f;
#pragma unroll
        for (int j = 0; j < 8; j++) s += part[tid * 8 + j];
        eM[tid] = s;
    }
    __syncthreads();

    // ---- phase D: per-n scores for 3 heads ----
    const float scale = 7.0710678118654752e-2f;  // 1/sqrt(200)
    float feat[14];
#pragma unroll
    for (int f = 0; f < 14; f++) feat[f] = sm[tid * 15 + f];
    float flag = sm[tid * 15 + 14];
    float loc = feat[2];
    float s0 = 0.f, s1 = 0.f, s2 = 0.f;
#pragma unroll
    for (int f = 0; f < 14; f++) {
        s0 += eM[f] * feat[f];
        s1 += eM[14 + f] * feat[f];
    }
#pragma unroll
    for (int f = 0; f < 7; f++) s2 += eM[28 + f] * feat[f];
    s0 *= scale; s1 *= scale; s2 *= scale;
    if (!((loc < subj_loc) && (flag == 1.f))) s0 = -1e9f;
    if (!((loc > subj_loc) && (flag == 1.f))) s1 = -1e9f;
    if (!(flag == 0.f)) s2 = -1e9f;

    // ---- phase E: softmax (3 heads batched) ----
    float m0 = s0, m1 = s1, m2 = s2;
    for (int off = 32; off; off >>= 1) {
        m0 = fmaxf(m0, __shfl_down(m0, off));
        m1 = fmaxf(m1, __shfl_down(m1, off));
        m2 = fmaxf(m2, __shfl_down(m2, off));
    }
    if (lane == 0) { wred[wave][0] = m0; wred[wave][1] = m1; wred[wave][2] = m2; }
    __syncthreads();
    m0 = fmaxf(fmaxf(wred[0][0], wred[1][0]), fmaxf(wred[2][0], wred[3][0]));
    m1 = fmaxf(fmaxf(wred[0][1], wred[1][1]), fmaxf(wred[2][1], wred[3][1]));
    m2 = fmaxf(fmaxf(wred[0][2], wred[1][2]), fmaxf(wred[2][2], wred[3][2]));
    float e0 = expf(s0 - m0), e1v = expf(s1 - m1), e2v = expf(s2 - m2);
    float z0 = e0, z1 = e1v, z2 = e2v;
    for (int off = 32; off; off >>= 1) {
        z0 += __shfl_down(z0, off);
        z1 += __shfl_down(z1, off);
        z2 += __shfl_down(z2, off);
    }
    __syncthreads();  // wred reuse
    if (lane == 0) { wred[wave][0] = z0; wred[wave][1] = z1; wred[wave][2] = z2; }
    __syncthreads();
    z0 = wred[0][0] + wred[1][0] + wred[2][0] + wred[3][0];
    z1 = wred[0][1] + wred[1][1] + wred[2][1] + wred[3][1];
    z2 = wred[0][2] + wred[1][2] + wred[2][2] + wred[3][2];

    // ---- phase F: store p ----
    psh[0 * 264 + tid] = e0 / z0;
    psh[1 * 264 + tid] = e1v / z1;
    psh[2 * 264 + tid] = e2v / z2;
    __syncthreads();

    // ---- phase G: c[h][f] = sum_n p[h][n] * feat[n][f] ----
    for (int vt = tid; vt < 280; vt += 256) {
        int d = vt >> 3, j = vt & 7;
        int h = d < 14 ? 0 : (d < 28 ? 1 : 2);
        int f = d - (h == 0 ? 0 : (h == 1 ? 14 : 28));
        const float* p = psh + h * 264;
        float s = 0.f;
        for (int n = j; n < NN; n += 8) s += p[n] * sm[n * 15 + f];
        part[d * 8 + j] = s;
    }
    __syncthreads();
    if (tid < 35) {
        float s = 0.f;
#pragma unroll
        for (int j = 0; j < 8; j++) s += part[tid * 8 + j];
        csh[tid] = s;
    }
    __syncthreads();

    // ---- phase H: out = c @ Wv, write + accumulate BN stats ----
    if (tid < VV) {
        const float* Wvs[3] = {upWv, dnWv, pvWv};
        float mh[3] = {m0, m1, m2};
        const int coff[3] = {0, 14, 28};
        const int Fs[3] = {14, 14, 7};
#pragma unroll
        for (int h = 0; h < 3; h++) {
            const float* Wv = Wvs[h];
            const float* c = csh + coff[h];
            float val = 0.f;
            for (int f = 0; f < Fs[h]; f++) val += c[f] * Wv[f * VV + tid];
            if (mh[h] == -1e9f) val = 0.f;  // empty mask -> zeros
            g_x[((size_t)h * BB + b) * VV + tid] = val;
            atomicAdd(&g_sum[h * VV + tid], val);
            atomicAdd(&g_ss[h * VV + tid], val * val);
        }
    }
}

// ---------------- K2: BN finalize+apply + trunk GEMM / e-MLP ----------------
// grid = 64 tiles * 4 groups. q<3: trunk head k=q. q==3: e-MLP. Partials atomicAdd'ed.
__global__ __launch_bounds__(256) void k_final(const float* __restrict__ merged, const float* __restrict__ a,
                                               const float* __restrict__ tW1, const float* __restrict__ tb1,
                                               const float* __restrict__ tW2, const float* __restrict__ tb2,
                                               const float* __restrict__ eW1, const float* __restrict__ eb1,
                                               const float* __restrict__ eW2, const float* __restrict__ eb2,
                                               const float* __restrict__ eW3, const float* __restrict__ eb3,
                                               const float* __restrict__ gamma, const float* __restrict__ beta,
                                               const float* __restrict__ ws,
                                               float* __restrict__ out) {
    int tile = blockIdx.x >> 2;
    int q = blockIdx.x & 3;
    int b0 = tile * BT;
    int tid = threadIdx.x;
    int lane = tid & 63, wave = tid >> 6;
    int w = tid;

    __shared__ __align__(16) float tT[VV * BT];  // transposed operand tile: [v][bb]
    __shared__ float bnA[VV], bnB[VV];           // BN affine: t = bnA[v]*x + bnB[v]
    __shared__ float redsh[4 * BT];
    __shared__ float esh[BT][4];

    const float* g_sum = ws + WS_SUM;
    const float* g_ss  = ws + WS_SS;
    const float* g_x   = ws + (WS_X_OFF / 4);

    float fin[BT];
#pragma unroll
    for (int bb = 0; bb < BT; bb++) fin[bb] = 0.f;

    if (q < 3) {
        // BN finalize for this head's 200 columns
        if (w < VV) {
            float S = g_sum[q * VV + w], S2 = g_ss[q * VV + w];
            float m = S * (1.f / BB);
            float var = S2 * (1.f / BB) - m * m;
            float rstd = rsqrtf(var + 1e-5f);
            float gv = gamma[w];
            bnA[w] = gv * rstd;
            bnB[w] = beta[w] - gv * rstd * m;
        }
        __syncthreads();
        // stage BN(x) transposed: tT[v*BT+bb]
        for (int idx = tid; idx < BT * VV; idx += 256) {
            int v = idx % VV, bb = idx / VV;
            float val = g_x[((size_t)q * BB + b0 + bb) * VV + v];
            tT[v * BT + bb] = bnA[v] * val + bnB[v];
        }
        __syncthreads();

        if (w < VV) {
            float acc[BT];
            float bias = tb1[q * VV + w];
#pragma unroll
            for (int bb = 0; bb < BT; bb++) acc[bb] = bias;
            const float* W1 = tW1 + (size_t)q * VV * VV + w;
            const float4* tT4 = (const float4*)tT;
#pragma unroll 4
            for (int v = 0; v < VV; v++) {
                float w1 = W1[(size_t)v * VV];
                float4 t0 = tT4[v * 4 + 0];
                float4 t1 = tT4[v * 4 + 1];
                float4 t2 = tT4[v * 4 + 2];
                float4 t3 = tT4[v * 4 + 3];
                acc[0]  += t0.x * w1; acc[1]  += t0.y * w1; acc[2]  += t0.z * w1; acc[3]  += t0.w * w1;
                acc[4]  += t1.x * w1; acc[5]  += t1.y * w1; acc[6]  += t1.z * w1; acc[7]  += t1.w * w1;
                acc[8]  += t2.x * w1; acc[9]  += t2.y * w1; acc[10] += t2.z * w1; acc[11] += t2.w * w1;
                acc[12] += t3.x * w1; acc[13] += t3.y * w1; acc[14] += t3.z * w1; acc[15] += t3.w * w1;
            }
            float w2 = tW2[q * VV + w];
#pragma unroll
            for (int bb = 0; bb < BT; bb++) {
                float h = acc[bb];
                h = h > 0.f ? h : expf(h) - 1.f;   // ELU
                fin[bb] = h * w2;
            }
        }
    } else {
        // e-MLP. phase 0: stage ego_t (features 3,4,5, a) for 16 rows
        if (tid < BT) {
            const float* mrow = merged + (size_t)(b0 + tid) * NN * 15;
            esh[tid][0] = mrow[3];
            esh[tid][1] = mrow[4];
            esh[tid][2] = mrow[5];
            esh[tid][3] = a[b0 + tid];
        }
        __syncthreads();
        // phase 1: q1 = relu(ego_t @ eW1 + eb1), stored transposed tT[v*BT+bb]
        if (w < VV) {
            float e0 = eW1[w], e1 = eW1[VV + w], e2 = eW1[2 * VV + w], e3 = eW1[3 * VV + w];
            float bias = eb1[w];
#pragma unroll
            for (int bb = 0; bb < BT; bb++) {
                float qv = bias + esh[bb][0] * e0 + esh[bb][1] * e1 + esh[bb][2] * e2 + esh[bb][3] * e3;
                tT[w * BT + bb] = fmaxf(qv, 0.f);
            }
        }
        __syncthreads();
        // phase 2: relu(q1 @ eW2 + eb2) . eW3
        if (w < VV) {
            float acc[BT];
            float bias = eb2[w];
#pragma unroll
            for (int bb = 0; bb < BT; bb++) acc[bb] = bias;
            const float* W2 = eW2 + w;
            const float4* tT4 = (const float4*)tT;
#pragma unroll 4
            for (int v = 0; v < VV; v++) {
                float w2v = W2[(size_t)v * VV];
                float4 t0 = tT4[v * 4 + 0];
                float4 t1 = tT4[v * 4 + 1];
                float4 t2 = tT4[v * 4 + 2];
                float4 t3 = tT4[v * 4 + 3];
                acc[0]  += t0.x * w2v; acc[1]  += t0.y * w2v; acc[2]  += t0.z * w2v; acc[3]  += t0.w * w2v;
                acc[4]  += t1.x * w2v; acc[5]  += t1.y * w2v; acc[6]  += t1.z * w2v; acc[7]  += t1.w * w2v;
                acc[8]  += t2.x * w2v; acc[9]  += t2.y * w2v; acc[10] += t2.z * w2v; acc[11] += t2.w * w2v;
                acc[12] += t3.x * w2v; acc[13] += t3.y * w2v; acc[14] += t3.z * w2v; acc[15] += t3.w * w2v;
            }
            float w3 = eW3[w];
#pragma unroll
            for (int bb = 0; bb < BT; bb++) fin[bb] = fmaxf(acc[bb], 0.f) * w3;
        }
    }

    // block-reduce fin[16] over threads
#pragma unroll
    for (int bb = 0; bb < BT; bb++)
        for (int off = 32; off; off >>= 1) fin[bb] += __shfl_down(fin[bb], off);
    if (lane == 0)
#pragma unroll
        for (int bb = 0; bb < BT; bb++) redsh[wave * BT + bb] = fin[bb];
    __syncthreads();
    if (tid < BT) {
        float tot = redsh[tid] + redsh[BT + tid] + redsh[2 * BT + tid] + redsh[3 * BT + tid];
        if (q == 3) tot += eb3[0] + tb2[0] + tb2[1] + tb2[2];  // constants added once
        atomicAdd(&out[b0 + tid], tot);
    }
}

extern "C" void kernel_launch(void* const* d_in, const int* in_sizes, int n_in,
                              void* d_out, int out_size, void* d_ws, size_t ws_size,
                              hipStream_t stream) {
    const float* merged = (const float*)d_in[0];
    const float* a      = (const float*)d_in[1];
    const float* upWq   = (const float*)d_in[2];
    const float* upWk   = (const float*)d_in[3];
    const float* upWv   = (const float*)d_in[4];
    const float* dnWq   = (const float*)d_in[5];
    const float* dnWk   = (const float*)d_in[6];
    const float* dnWv   = (const float*)d_in[7];
    const float* pvWq   = (const float*)d_in[8];
    const float* pvWk   = (const float*)d_in[9];
    const float* pvWv   = (const float*)d_in[10];
    const float* tW1    = (const float*)d_in[11];
    const float* tb1    = (const float*)d_in[12];
    const float* tW2    = (const float*)d_in[13];
    const float* tb2    = (const float*)d_in[14];
    const float* eW1    = (const float*)d_in[15];
    const float* eb1    = (const float*)d_in[16];
    const float* eW2    = (const float*)d_in[17];
    const float* eb2    = (const float*)d_in[18];
    const float* eW3    = (const float*)d_in[19];
    const float* eb3    = (const float*)d_in[20];
    const float* gamma  = (const float*)d_in[21];
    const float* beta   = (const float*)d_in[22];
    float* out = (float*)d_out;
    float* ws = (float*)d_ws;

    // zero BN-stat accumulators + output (both tiny, independent)
    hipMemsetAsync(ws, 0, 2 * 3 * VV * sizeof(float), stream);
    hipMemsetAsync(out, 0, (size_t)out_size * sizeof(float), stream);
    hipLaunchKernelGGL(k_attn, dim3(BB), dim3(256), 0, stream, merged, a,
                       upWq, upWk, upWv, dnWq, dnWk, dnWv, pvWq, pvWk, pvWv, ws);
    hipLaunchKernelGGL(k_final, dim3(64 * 4), dim3(256), 0, stream, merged, a,
                       tW1, tb1, tW2, tb2, eW1, eb1, eW2, eb2, eW3, eb3, gamma, beta, ws, out);
}

// Round 4
// 144.738 us; speedup vs baseline: 1.3377x; 1.3377x over previous
//
#include <hip/hip_runtime.h>
#include <math.h>

#define BB 1024
#define NN 256
#define VV 200
#define BT 8          // batch rows per k_final tile
#define NSH 16        // BN-stat atomic shards

// d_ws layout (floats):
//   [0    .. 256)        g_M   (245 used: up[98] | dn[98]@98 | pv[49]@196)
//   [256  .. 256+19200)  stats: g_sum[NSH][600] then g_ss[NSH][600]
//   [19456.. +614400)    g_x [3][1024][200]
#define WS_M    0
#define WS_STAT 256
#define WS_X    19456

// ---------------- K0: M = Wq @ Wk^T (3 blocks) + zero stats/out ----------------
__global__ __launch_bounds__(256) void k_prep(const float* __restrict__ upWq, const float* __restrict__ upWk,
                                              const float* __restrict__ dnWq, const float* __restrict__ dnWk,
                                              const float* __restrict__ pvWq, const float* __restrict__ pvWk,
                                              float* __restrict__ ws, float* __restrict__ out) {
    __shared__ float wq[7 * VV];
    __shared__ float wk[14 * VV];
    int blk = blockIdx.x, tid = threadIdx.x;
    // zero stats shards + output (split across the 3 blocks)
    float* stat = ws + WS_STAT;
    for (int i = blk * 256 + tid; i < 2 * NSH * 600; i += 768) stat[i] = 0.f;
    for (int i = blk * 256 + tid; i < BB; i += 768) out[i] = 0.f;

    const float* Wq = blk == 0 ? upWq : (blk == 1 ? dnWq : pvWq);
    const float* Wk = blk == 0 ? upWk : (blk == 1 ? dnWk : pvWk);
    int F = (blk == 2) ? 7 : 14;
    int off = blk == 0 ? 0 : (blk == 1 ? 98 : 196);
    for (int i = tid; i < 7 * VV; i += 256) wq[i] = Wq[i];
    for (int i = tid; i < F * VV; i += 256) wk[i] = Wk[i];
    __syncthreads();
    if (tid < 7 * F) {
        int i = tid / F, f = tid % F;
        float s = 0.f;
        for (int v = 0; v < VV; v++) s += wq[i * VV + v] * wk[f * VV + v];
        ws[WS_M + off + tid] = s;   // layout: [h] i*F + f
    }
}

// ---------------- K1: attention — ONE WAVE PER ROW, shuffle-only cross-lane ----------------
// grid 256 blocks x 256 threads; wave w handles row blockIdx*4+w. Single __syncthreads (staging).
__global__ __launch_bounds__(256) void k_attn(
    const float* __restrict__ merged, const float* __restrict__ a,
    const float* __restrict__ upWv, const float* __restrict__ dnWv, const float* __restrict__ pvWv,
    float* __restrict__ ws) {
    int tid = threadIdx.x;
    int lane = tid & 63, wave = tid >> 6;
    int b = blockIdx.x * 4 + wave;

    __shared__ float sm[4 * NN * 15];   // 61440 B: 4 rows
    // ---- coalesced staging of 4 rows ----
    const float4* g4 = (const float4*)(merged + (size_t)blockIdx.x * 4 * NN * 15);
    float4* s4p = (float4*)sm;
    for (int i = tid; i < 4 * NN * 15 / 4; i += 256) s4p[i] = g4[i];
    __syncthreads();

    const float* row = sm + wave * NN * 15;
    const float* gM = ws + WS_M;
    float* g_sum = ws + WS_STAT;
    float* g_ss  = ws + WS_STAT + NSH * 600;
    float* g_x   = ws + WS_X;

    float ab = a[b];
    float subj_id = row[0];
    float subj_loc = row[2];
    float e1 = row[1], e2 = row[2], e3 = row[3], e4 = row[4], e5 = row[5], e6 = ab;

    // ---- per-lane features for 4 n's (corrected in registers) ----
    float feat[4][14];
    float flag[4];
#pragma unroll
    for (int k = 0; k < 4; k++) {
        int base = (lane + 64 * k) * 15;
#pragma unroll
        for (int f = 0; f < 14; f++) feat[k][f] = row[base + f];
        flag[k] = row[base + 14];
        feat[k][0] -= subj_id;
        feat[k][7] -= subj_id;
    }
    if (lane == 0) feat[0][6] = ab;   // n==0 : merged[:,0,6]=a

    // ---- eM[d] = sum_i ego[i] * M_h[i][f]   (lane d<35 computes one) ----
    float em = 0.f;
    if (lane < 35) {
        int h = lane < 14 ? 0 : (lane < 28 ? 1 : 2);
        int f = lane - (h == 0 ? 0 : (h == 1 ? 14 : 28));
        int F = (h == 2) ? 7 : 14;
        const float* M = gM + (h == 0 ? 0 : (h == 1 ? 98 : 196));
        em = e1 * M[1 * F + f] + e2 * M[2 * F + f] + e3 * M[3 * F + f] +
             e4 * M[4 * F + f] + e5 * M[5 * F + f] + e6 * M[6 * F + f];
    }

    // ---- scores via 35 broadcasts ----
    float s0[4] = {0, 0, 0, 0}, s1[4] = {0, 0, 0, 0}, s2[4] = {0, 0, 0, 0};
#pragma unroll
    for (int f = 0; f < 14; f++) {
        float bv = __shfl(em, f);
#pragma unroll
        for (int k = 0; k < 4; k++) s0[k] += bv * feat[k][f];
    }
#pragma unroll
    for (int f = 0; f < 14; f++) {
        float bv = __shfl(em, 14 + f);
#pragma unroll
        for (int k = 0; k < 4; k++) s1[k] += bv * feat[k][f];
    }
#pragma unroll
    for (int f = 0; f < 7; f++) {
        float bv = __shfl(em, 28 + f);
#pragma unroll
        for (int k = 0; k < 4; k++) s2[k] += bv * feat[k][f];
    }

    const float scale = 7.0710678118654752e-2f;  // 1/sqrt(200)
#pragma unroll
    for (int k = 0; k < 4; k++) {
        float loc = feat[k][2];
        s0[k] = ((loc < subj_loc) && (flag[k] == 1.f)) ? s0[k] * scale : -1e9f;
        s1[k] = ((loc > subj_loc) && (flag[k] == 1.f)) ? s1[k] * scale : -1e9f;
        s2[k] = (flag[k] == 0.f) ? s2[k] * scale : -1e9f;
    }

    // ---- softmax: wave-wide max/sum via xor butterfly ----
    float m0 = fmaxf(fmaxf(s0[0], s0[1]), fmaxf(s0[2], s0[3]));
    float m1 = fmaxf(fmaxf(s1[0], s1[1]), fmaxf(s1[2], s1[3]));
    float m2 = fmaxf(fmaxf(s2[0], s2[1]), fmaxf(s2[2], s2[3]));
#pragma unroll
    for (int off = 32; off; off >>= 1) {
        m0 = fmaxf(m0, __shfl_xor(m0, off));
        m1 = fmaxf(m1, __shfl_xor(m1, off));
        m2 = fmaxf(m2, __shfl_xor(m2, off));
    }
    float p0[4], p1[4], p2[4];
    float z0 = 0.f, z1 = 0.f, z2 = 0.f;
#pragma unroll
    for (int k = 0; k < 4; k++) {
        p0[k] = expf(s0[k] - m0); z0 += p0[k];
        p1[k] = expf(s1[k] - m1); z1 += p1[k];
        p2[k] = expf(s2[k] - m2); z2 += p2[k];
    }
#pragma unroll
    for (int off = 32; off; off >>= 1) {
        z0 += __shfl_xor(z0, off);
        z1 += __shfl_xor(z1, off);
        z2 += __shfl_xor(z2, off);
    }
    float r0 = 1.f / z0, r1 = 1.f / z1, r2 = 1.f / z2;
#pragma unroll
    for (int k = 0; k < 4; k++) { p0[k] *= r0; p1[k] *= r1; p2[k] *= r2; }

    // ---- c[h][f] partials then 35-wide xor butterfly ----
    float pc[35];
#pragma unroll
    for (int f = 0; f < 14; f++) {
        float c0 = 0.f, c1 = 0.f;
#pragma unroll
        for (int k = 0; k < 4; k++) { c0 += p0[k] * feat[k][f]; c1 += p1[k] * feat[k][f]; }
        pc[f] = c0; pc[14 + f] = c1;
    }
#pragma unroll
    for (int f = 0; f < 7; f++) {
        float c2 = 0.f;
#pragma unroll
        for (int k = 0; k < 4; k++) c2 += p2[k] * feat[k][f];
        pc[28 + f] = c2;
    }
#pragma unroll
    for (int off = 32; off; off >>= 1)
#pragma unroll
        for (int j = 0; j < 35; j++) pc[j] += __shfl_xor(pc[j], off);
    // all lanes now hold the full c vectors

    // ---- out[v] = c_h @ Wv_h, write g_x + sharded BN-stat atomics ----
    int shard = blockIdx.x & (NSH - 1);
    const float* Wvs[3] = {upWv, dnWv, pvWv};
    float mh[3] = {m0, m1, m2};
    const int coff[3] = {0, 14, 28};
#pragma unroll
    for (int h = 0; h < 3; h++) {
        const float* Wv = Wvs[h];
        const float* c = pc + coff[h];
        int F = (h == 2) ? 7 : 14;
        bool empty = (mh[h] == -1e9f);
#pragma unroll
        for (int slot = 0; slot < 4; slot++) {
            int v = lane + 64 * slot;
            if (v < VV) {
                float val = 0.f;
                for (int f = 0; f < F; f++) val += c[f] * Wv[f * VV + v];
                if (empty) val = 0.f;
                g_x[((size_t)h * BB + b) * VV + v] = val;
                atomicAdd(&g_sum[shard * 600 + h * VV + v], val);
                atomicAdd(&g_ss[shard * 600 + h * VV + v], val * val);
            }
        }
    }
}

// ---------------- K2: BN finalize+apply + trunk GEMM / e-MLP ----------------
// grid = 128 tiles * 4 groups (BT=8 rows). q<3: trunk head q. q==3: e-MLP.
__global__ __launch_bounds__(256) void k_final(const float* __restrict__ merged, const float* __restrict__ a,
                                               const float* __restrict__ tW1, const float* __restrict__ tb1,
                                               const float* __restrict__ tW2, const float* __restrict__ tb2,
                                               const float* __restrict__ eW1, const float* __restrict__ eb1,
                                               const float* __restrict__ eW2, const float* __restrict__ eb2,
                                               const float* __restrict__ eW3, const float* __restrict__ eb3,
                                               const float* __restrict__ gamma, const float* __restrict__ beta,
                                               const float* __restrict__ ws,
                                               float* __restrict__ out) {
    int tile = blockIdx.x >> 2;
    int q = blockIdx.x & 3;
    int b0 = tile * BT;
    int tid = threadIdx.x;
    int lane = tid & 63, wave = tid >> 6;
    int w = tid;

    __shared__ __align__(16) float tT[VV * BT];  // [v][bb]
    __shared__ float redsh[4 * BT];
    __shared__ float esh[BT][4];

    const float* g_sum = ws + WS_STAT;
    const float* g_ss  = ws + WS_STAT + NSH * 600;
    const float* g_x   = ws + WS_X;

    float fin[BT];
#pragma unroll
    for (int bb = 0; bb < BT; bb++) fin[bb] = 0.f;

    if (q < 3) {
        // BN finalize (sum NSH shards) -> affine in registers, broadcast via LDS staging
        __shared__ float bnA[VV], bnB[VV];
        if (w < VV) {
            float S = 0.f, S2 = 0.f;
#pragma unroll
            for (int s = 0; s < NSH; s++) {
                S += g_sum[s * 600 + q * VV + w];
                S2 += g_ss[s * 600 + q * VV + w];
            }
            float m = S * (1.f / BB);
            float var = S2 * (1.f / BB) - m * m;
            float rstd = rsqrtf(var + 1e-5f);
            float gv = gamma[w];
            bnA[w] = gv * rstd;
            bnB[w] = beta[w] - gv * rstd * m;
        }
        __syncthreads();
        for (int idx = tid; idx < BT * VV; idx += 256) {
            int v = idx % VV, bb = idx / VV;
            float val = g_x[((size_t)q * BB + b0 + bb) * VV + v];
            tT[v * BT + bb] = bnA[v] * val + bnB[v];
        }
        __syncthreads();

        if (w < VV) {
            float acc[BT];
            float bias = tb1[q * VV + w];
#pragma unroll
            for (int bb = 0; bb < BT; bb++) acc[bb] = bias;
            const float* W1 = tW1 + (size_t)q * VV * VV + w;
            const float4* tT4 = (const float4*)tT;
#pragma unroll 8
            for (int v = 0; v < VV; v++) {
                float w1 = W1[(size_t)v * VV];
                float4 t0 = tT4[v * 2 + 0];
                float4 t1 = tT4[v * 2 + 1];
                acc[0] += t0.x * w1; acc[1] += t0.y * w1; acc[2] += t0.z * w1; acc[3] += t0.w * w1;
                acc[4] += t1.x * w1; acc[5] += t1.y * w1; acc[6] += t1.z * w1; acc[7] += t1.w * w1;
            }
            float w2 = tW2[q * VV + w];
#pragma unroll
            for (int bb = 0; bb < BT; bb++) {
                float h = acc[bb];
                h = h > 0.f ? h : expf(h) - 1.f;   // ELU
                fin[bb] = h * w2;
            }
        }
    } else {
        if (tid < BT) {
            const float* mrow = merged + (size_t)(b0 + tid) * NN * 15;
            esh[tid][0] = mrow[3];
            esh[tid][1] = mrow[4];
            esh[tid][2] = mrow[5];
            esh[tid][3] = a[b0 + tid];
        }
        __syncthreads();
        if (w < VV) {
            float e0 = eW1[w], e1 = eW1[VV + w], e2 = eW1[2 * VV + w], e3 = eW1[3 * VV + w];
            float bias = eb1[w];
#pragma unroll
            for (int bb = 0; bb < BT; bb++) {
                float qv = bias + esh[bb][0] * e0 + esh[bb][1] * e1 + esh[bb][2] * e2 + esh[bb][3] * e3;
                tT[w * BT + bb] = fmaxf(qv, 0.f);
            }
        }
        __syncthreads();
        if (w < VV) {
            float acc[BT];
            float bias = eb2[w];
#pragma unroll
            for (int bb = 0; bb < BT; bb++) acc[bb] = bias;
            const float* W2 = eW2 + w;
            const float4* tT4 = (const float4*)tT;
#pragma unroll 8
            for (int v = 0; v < VV; v++) {
                float w2v = W2[(size_t)v * VV];
                float4 t0 = tT4[v * 2 + 0];
                float4 t1 = tT4[v * 2 + 1];
                acc[0] += t0.x * w2v; acc[1] += t0.y * w2v; acc[2] += t0.z * w2v; acc[3] += t0.w * w2v;
                acc[4] += t1.x * w2v; acc[5] += t1.y * w2v; acc[6] += t1.z * w2v; acc[7] += t1.w * w2v;
            }
            float w3 = eW3[w];
#pragma unroll
            for (int bb = 0; bb < BT; bb++) fin[bb] = fmaxf(acc[bb], 0.f) * w3;
        }
    }

    // block-reduce fin[BT]
#pragma unroll
    for (int bb = 0; bb < BT; bb++)
#pragma unroll
        for (int off = 32; off; off >>= 1) fin[bb] += __shfl_xor(fin[bb], off);
    if (lane == 0)
#pragma unroll
        for (int bb = 0; bb < BT; bb++) redsh[wave * BT + bb] = fin[bb];
    __syncthreads();
    if (tid < BT) {
        float tot = redsh[tid] + redsh[BT + tid] + redsh[2 * BT + tid] + redsh[3 * BT + tid];
        if (q == 3) tot += eb3[0] + tb2[0] + tb2[1] + tb2[2];
        atomicAdd(&out[b0 + tid], tot);
    }
}

extern "C" void kernel_launch(void* const* d_in, const int* in_sizes, int n_in,
                              void* d_out, int out_size, void* d_ws, size_t ws_size,
                              hipStream_t stream) {
    const float* merged = (const float*)d_in[0];
    const float* a      = (const float*)d_in[1];
    const float* upWq   = (const float*)d_in[2];
    const float* upWk   = (const float*)d_in[3];
    const float* upWv   = (const float*)d_in[4];
    const float* dnWq   = (const float*)d_in[5];
    const float* dnWk   = (const float*)d_in[6];
    const float* dnWv   = (const float*)d_in[7];
    const float* pvWq   = (const float*)d_in[8];
    const float* pvWk   = (const float*)d_in[9];
    const float* pvWv   = (const float*)d_in[10];
    const float* tW1    = (const float*)d_in[11];
    const float* tb1    = (const float*)d_in[12];
    const float* tW2    = (const float*)d_in[13];
    const float* tb2    = (const float*)d_in[14];
    const float* eW1    = (const float*)d_in[15];
    const float* eb1    = (const float*)d_in[16];
    const float* eW2    = (const float*)d_in[17];
    const float* eb2    = (const float*)d_in[18];
    const float* eW3    = (const float*)d_in[19];
    const float* eb3    = (const float*)d_in[20];
    const float* gamma  = (const float*)d_in[21];
    const float* beta   = (const float*)d_in[22];
    float* out = (float*)d_out;
    float* ws = (float*)d_ws;

    hipLaunchKernelGGL(k_prep, dim3(3), dim3(256), 0, stream, upWq, upWk, dnWq, dnWk, pvWq, pvWk, ws, out);
    hipLaunchKernelGGL(k_attn, dim3(BB / 4), dim3(256), 0, stream, merged, a, upWv, dnWv, pvWv, ws);
    hipLaunchKernelGGL(k_final, dim3((BB / BT) * 4), dim3(256), 0, stream, merged, a,
                       tW1, tb1, tW2, tb2, eW1, eb1, eW2, eb2, eW3, eb3, gamma, beta, ws, out);
}